// Round 1
// baseline (861.912 us; speedup 1.0000x reference)
//
#include <hip/hip_runtime.h>
#include <hip/hip_bf16.h>
#include <math.h>

// Problem constants
#define NUM_CLASSES 9
#define BATCH 8
#define CH 768
#define HP 128          // H/4
#define WP 128          // W/4
#define NPIX (BATCH*HP*WP)      // 131072
#define PLANE (HP*WP)           // 16384 pixels per (b,k) plane

// Workspace layout (bytes)
#define WS_COUNTS   0                 // int[9]
#define WS_ROWSQ    64                // float[9]
#define WS_LOSS     128               // float[1]
#define WS_SUMS     256               // float[9*768]  -> ends 27904
#define WS_PNT      27904             // float[768*9] (k-major) -> ends 55552
#define WS_LABELS   55552             // uchar[131072] -> ends 186624
#define WS_DOT      186880            // float[9*131072] -> ends 4905472
#define WS_ZERO_BYTES 27904           // memset counts+rowsq+loss+sums

__device__ __forceinline__ float wave_reduce_sum(float v) {
#pragma unroll
    for (int off = 32; off > 0; off >>= 1) v += __shfl_down(v, off, 64);
    return v;
}

// ---------------- Kernel A: downsample labels + class counts -------------
__global__ __launch_bounds__(256)
void k_labels(const int* __restrict__ gt, unsigned char* __restrict__ labels,
              int* __restrict__ counts) {
    __shared__ int hist[NUM_CLASSES];
    int t = threadIdx.x;
    if (t < NUM_CLASSES) hist[t] = 0;
    __syncthreads();
    int n = blockIdx.x * 256 + t;                 // n < 131072
    int b = n >> 14;
    int rem = n & 16383;
    int i = rem >> 7, j = rem & 127;
    int lab = gt[b * 262144 + i * 2048 + j * 4];  // gt[b, 4i, 4j]
    labels[n] = (unsigned char)lab;
    atomicAdd(&hist[lab], 1);
    __syncthreads();
    if (t < NUM_CLASSES) atomicAdd(&counts[t], hist[t]);
}

// ---------------- Kernel B: per-class feature sums ------------------------
// one block per (b,k) plane; float4 over 16384 pixels; acc[9] in registers
__global__ __launch_bounds__(256)
void k_segsum(const float4* __restrict__ feats4, const unsigned int* __restrict__ lab4,
              float* __restrict__ sums) {
    int bk = blockIdx.x;                // 0..6143
    int b  = bk / CH;
    int k  = bk - b * CH;
    const float4* plane = feats4 + (size_t)bk * (PLANE / 4);
    const unsigned int* labs = lab4 + b * (PLANE / 4);

    float acc[NUM_CLASSES];
#pragma unroll
    for (int c = 0; c < NUM_CLASSES; c++) acc[c] = 0.f;

    for (int i = threadIdx.x; i < PLANE / 4; i += 256) {
        float4 v = plane[i];
        unsigned int L = labs[i];
        int l0 = L & 255, l1 = (L >> 8) & 255, l2 = (L >> 16) & 255, l3 = (L >> 24);
#pragma unroll
        for (int c = 0; c < NUM_CLASSES; c++) {
            float s = (l0 == c ? v.x : 0.f);
            s += (l1 == c ? v.y : 0.f);
            s += (l2 == c ? v.z : 0.f);
            s += (l3 == c ? v.w : 0.f);
            acc[c] += s;
        }
    }
    int lane = threadIdx.x & 63;
#pragma unroll
    for (int c = 0; c < NUM_CLASSES; c++) {
        float v = wave_reduce_sum(acc[c]);
        if (lane == 0) atomicAdd(&sums[c * CH + k], v);
    }
}

// ---------------- Kernel C: prototype update + row l2norm -----------------
// 9 blocks x 256 threads; writes pnT[k*9 + c] (k-major for kernel D)
__global__ __launch_bounds__(256)
void k_protos(const float* __restrict__ sums, const int* __restrict__ counts,
              const float* __restrict__ proto_in, float* __restrict__ pnT) {
    int c = blockIdx.x;
    int cnt = counts[c];
    float inv = 1.0f / fmaxf((float)cnt, 1.0f);
    bool pres = cnt > 0;

    float vals[3];
    float sq = 0.f;
#pragma unroll
    for (int r = 0; r < 3; r++) {
        int k = threadIdx.x + r * 256;
        float p = proto_in[c * CH + k];
        float m = sums[c * CH + k] * inv;
        float u = 0.99f * m + 0.01f * p;
        float v = pres ? u : p;
        vals[r] = v;
        sq += v * v;
    }
    sq = wave_reduce_sum(sq);
    __shared__ float red[4];
    int wid = threadIdx.x >> 6, lane = threadIdx.x & 63;
    if (lane == 0) red[wid] = sq;
    __syncthreads();
    float tot = red[0] + red[1] + red[2] + red[3];
    float nrm = fmaxf(sqrtf(tot), 1e-12f);
    float rinv = 1.0f / nrm;
#pragma unroll
    for (int r = 0; r < 3; r++) {
        int k = threadIdx.x + r * 256;
        pnT[k * NUM_CLASSES + c] = vals[r] * rinv;
    }
}

// ---------------- Kernel D: dot products + per-class sum of squares -------
// 512 blocks x 256 threads, one pixel per thread; loops all 768 channels.
__global__ __launch_bounds__(256)
void k_dot(const float* __restrict__ feats, const float* __restrict__ pnT,
           float* __restrict__ dot, float* __restrict__ rowsq) {
    int n = blockIdx.x * 256 + threadIdx.x;       // pixel id
    int b = n >> 14;
    int p = n & 16383;
    const float* base = feats + (size_t)b * CH * PLANE + p;

    float d[NUM_CLASSES];
#pragma unroll
    for (int c = 0; c < NUM_CLASSES; c++) d[c] = 0.f;

#pragma unroll 8
    for (int k = 0; k < CH; k++) {
        float v = base[(size_t)k * PLANE];
#pragma unroll
        for (int c = 0; c < NUM_CLASSES; c++)
            d[c] = fmaf(pnT[k * NUM_CLASSES + c], v, d[c]);
    }

    int lane = threadIdx.x & 63;
#pragma unroll
    for (int c = 0; c < NUM_CLASSES; c++) {
        dot[(size_t)c * NPIX + n] = d[c];
        float s = wave_reduce_sum(d[c] * d[c]);
        if (lane == 0) atomicAdd(&rowsq[c], s);
    }
}

// ---------------- Kernel E: log-softmax + picked + loss sum ---------------
__global__ __launch_bounds__(256)
void k_loss(const float* __restrict__ dot, const float* __restrict__ rowsq,
            const unsigned char* __restrict__ labels, float* __restrict__ lossacc) {
    int n = blockIdx.x * 256 + threadIdx.x;
    float l[NUM_CLASSES];
#pragma unroll
    for (int c = 0; c < NUM_CLASSES; c++) {
        float nrm = fmaxf(sqrtf(rowsq[c]), 1e-12f);
        l[c] = (dot[(size_t)c * NPIX + n] / nrm) * 10.0f;   // /TEMPERATURE
    }
    float m = l[0];
#pragma unroll
    for (int c = 1; c < NUM_CLASSES; c++) m = fmaxf(m, l[c]);
    float s = 0.f;
#pragma unroll
    for (int c = 0; c < NUM_CLASSES; c++) s += expf(l[c] - m);
    float lse = m + logf(s);

    int lab = labels[n];
    float lv = l[0];
#pragma unroll
    for (int c = 1; c < NUM_CLASSES; c++) lv = (lab == c) ? l[c] : lv;
    float picked = lv - lse;

    picked = wave_reduce_sum(picked);
    __shared__ float red[4];
    int wid = threadIdx.x >> 6, lane = threadIdx.x & 63;
    if (lane == 0) red[wid] = picked;
    __syncthreads();
    if (threadIdx.x == 0) {
        atomicAdd(lossacc, red[0] + red[1] + red[2] + red[3]);
    }
}

// ---------------- Kernel F: finalize --------------------------------------
__global__ void k_fin(const float* __restrict__ lossacc, float* __restrict__ out) {
    out[0] = -lossacc[0] * (1.0f / (float)NPIX);
}

extern "C" void kernel_launch(void* const* d_in, const int* in_sizes, int n_in,
                              void* d_out, int out_size, void* d_ws, size_t ws_size,
                              hipStream_t stream) {
    const float* feats    = (const float*)d_in[0];
    const int*   gt       = (const int*)d_in[1];
    const float* protos   = (const float*)d_in[2];
    float* out = (float*)d_out;

    char* ws = (char*)d_ws;
    int*   counts  = (int*)(ws + WS_COUNTS);
    float* rowsq   = (float*)(ws + WS_ROWSQ);
    float* lossacc = (float*)(ws + WS_LOSS);
    float* sums    = (float*)(ws + WS_SUMS);
    float* pnT     = (float*)(ws + WS_PNT);
    unsigned char* labels = (unsigned char*)(ws + WS_LABELS);
    float* dot     = (float*)(ws + WS_DOT);

    hipMemsetAsync(d_ws, 0, WS_ZERO_BYTES, stream);

    k_labels<<<NPIX / 256, 256, 0, stream>>>(gt, labels, counts);
    k_segsum<<<BATCH * CH, 256, 0, stream>>>((const float4*)feats,
                                             (const unsigned int*)labels, sums);
    k_protos<<<NUM_CLASSES, 256, 0, stream>>>(sums, counts, protos, pnT);
    k_dot<<<NPIX / 256, 256, 0, stream>>>(feats, pnT, dot, rowsq);
    k_loss<<<NPIX / 256, 256, 0, stream>>>(dot, rowsq, labels, lossacc);
    k_fin<<<1, 1, 0, stream>>>(lossacc, out);
}

// Round 2
// 695.076 us; speedup vs baseline: 1.2400x; 1.2400x over previous
//
#include <hip/hip_runtime.h>
#include <hip/hip_bf16.h>
#include <math.h>

// Problem constants
#define NUM_CLASSES 9
#define BATCH 8
#define CH 768
#define PLANE 16384             // (H/4)*(W/4)
#define NPIX (BATCH*PLANE)      // 131072
#define NP4 (NPIX/4)            // 32768 float4 pixel-groups

// Workspace layout (bytes)
#define WS_COUNTS   0                 // int[9]
#define WS_ROWSQ    64                // float[9]
#define WS_LOSS     128               // float[1]
#define WS_SUMS     256               // float[9*768]  -> ends 27904
#define WS_PNT      27904             // float[768*9] (k-major) -> ends 55552
#define WS_LABELS   55552             // uchar[131072] -> ends 186624
#define WS_DOT      186880            // float[9*131072] -> ends 4905472
#define WS_DOTP     4905472           // float[nchunk*9*131072] partial dots
#define WS_ZERO_BYTES 27904           // memset counts+rowsq+loss+sums

__device__ __forceinline__ float wave_reduce_sum(float v) {
#pragma unroll
    for (int off = 32; off > 0; off >>= 1) v += __shfl_down(v, off, 64);
    return v;
}

// ---------------- Kernel A: downsample labels + class counts -------------
__global__ __launch_bounds__(256)
void k_labels(const int* __restrict__ gt, unsigned char* __restrict__ labels,
              int* __restrict__ counts) {
    __shared__ int hist[NUM_CLASSES];
    int t = threadIdx.x;
    if (t < NUM_CLASSES) hist[t] = 0;
    __syncthreads();
    int n = blockIdx.x * 256 + t;                 // n < 131072
    int b = n >> 14;
    int rem = n & 16383;
    int i = rem >> 7, j = rem & 127;
    int lab = gt[b * 262144 + i * 2048 + j * 4];  // gt[b, 4i, 4j]
    labels[n] = (unsigned char)lab;
    atomicAdd(&hist[lab], 1);
    __syncthreads();
    if (t < NUM_CLASSES) atomicAdd(&counts[t], hist[t]);
}

// ---------------- Kernel B: per-class feature sums ------------------------
// one block per (b,k) plane; batched float4 loads; acc[9] in registers
__device__ __forceinline__ void seg_acc(float* acc, float4 v, unsigned int L) {
    int l0 = L & 255, l1 = (L >> 8) & 255, l2 = (L >> 16) & 255, l3 = (int)(L >> 24);
#pragma unroll
    for (int c = 0; c < NUM_CLASSES; c++) {
        float s = (l0 == c ? v.x : 0.f);
        s += (l1 == c ? v.y : 0.f);
        s += (l2 == c ? v.z : 0.f);
        s += (l3 == c ? v.w : 0.f);
        acc[c] += s;
    }
}

__global__ __launch_bounds__(256)
void k_segsum(const float4* __restrict__ feats4, const unsigned int* __restrict__ lab4,
              float* __restrict__ sums) {
    int bk = blockIdx.x;                // 0..6143
    int b  = bk / CH;
    int k  = bk - b * CH;
    const float4* plane = feats4 + ((size_t)bk << 12);
    const unsigned int* labs = lab4 + (b << 12);

    float acc[NUM_CLASSES];
#pragma unroll
    for (int c = 0; c < NUM_CLASSES; c++) acc[c] = 0.f;

    int i = threadIdx.x;
#pragma unroll
    for (int r = 0; r < 4; r++) {
        // batch 4 loads to maximize memory-level parallelism
        float4 v0 = plane[i];           unsigned int L0 = labs[i];
        float4 v1 = plane[i + 256];     unsigned int L1 = labs[i + 256];
        float4 v2 = plane[i + 512];     unsigned int L2 = labs[i + 512];
        float4 v3 = plane[i + 768];     unsigned int L3 = labs[i + 768];
        seg_acc(acc, v0, L0);
        seg_acc(acc, v1, L1);
        seg_acc(acc, v2, L2);
        seg_acc(acc, v3, L3);
        i += 1024;
    }
    int lane = threadIdx.x & 63;
#pragma unroll
    for (int c = 0; c < NUM_CLASSES; c++) {
        float v = wave_reduce_sum(acc[c]);
        if (lane == 0) atomicAdd(&sums[c * CH + k], v);
    }
}

// ---------------- Kernel C: prototype update + row l2norm -----------------
__global__ __launch_bounds__(256)
void k_protos(const float* __restrict__ sums, const int* __restrict__ counts,
              const float* __restrict__ proto_in, float* __restrict__ pnT) {
    int c = blockIdx.x;
    int cnt = counts[c];
    float inv = 1.0f / fmaxf((float)cnt, 1.0f);
    bool pres = cnt > 0;

    float vals[3];
    float sq = 0.f;
#pragma unroll
    for (int r = 0; r < 3; r++) {
        int k = threadIdx.x + r * 256;
        float p = proto_in[c * CH + k];
        float m = sums[c * CH + k] * inv;
        float u = 0.99f * m + 0.01f * p;
        float v = pres ? u : p;
        vals[r] = v;
        sq += v * v;
    }
    sq = wave_reduce_sum(sq);
    __shared__ float red[4];
    int wid = threadIdx.x >> 6, lane = threadIdx.x & 63;
    if (lane == 0) red[wid] = sq;
    __syncthreads();
    float tot = red[0] + red[1] + red[2] + red[3];
    float nrm = fmaxf(sqrtf(tot), 1e-12f);
    float rinv = 1.0f / nrm;
#pragma unroll
    for (int r = 0; r < 3; r++) {
        int k = threadIdx.x + r * 256;
        pnT[k * NUM_CLASSES + c] = vals[r] * rinv;
    }
}

// ---------------- Kernel D: dot products (K-chunked, float4) --------------
// NCHUNK k-chunks x 128 blocks x 256 threads; 4 pixels per thread.
template<int NCHUNK>
__global__ __launch_bounds__(256, 2)
void k_dot(const float4* __restrict__ feats4, const float* __restrict__ pnT,
           float4* __restrict__ dotp) {
    constexpr int KC = CH / NCHUNK;
    int g = blockIdx.x >> 7;                       // k-chunk id
    int t = ((blockIdx.x & 127) << 8) + threadIdx.x;  // pixel-group 0..32767
    int b = t >> 12;
    int p4 = t & 4095;
    const float4* base = feats4 + (((size_t)(b * CH + g * KC)) << 12) + p4;
    const float* pw = pnT + g * KC * NUM_CLASSES;

    float4 acc[NUM_CLASSES];
#pragma unroll
    for (int c = 0; c < NUM_CLASSES; c++) acc[c] = make_float4(0.f, 0.f, 0.f, 0.f);

#pragma unroll 4
    for (int k = 0; k < KC; k++) {
        float4 v = base[(size_t)k << 12];
#pragma unroll
        for (int c = 0; c < NUM_CLASSES; c++) {
            float w = pw[k * NUM_CLASSES + c];
            acc[c].x = fmaf(w, v.x, acc[c].x);
            acc[c].y = fmaf(w, v.y, acc[c].y);
            acc[c].z = fmaf(w, v.z, acc[c].z);
            acc[c].w = fmaf(w, v.w, acc[c].w);
        }
    }
#pragma unroll
    for (int c = 0; c < NUM_CLASSES; c++)
        dotp[(size_t)(g * NUM_CLASSES + c) * NP4 + t] = acc[c];
}

// ---------------- Kernel D2: combine partials + per-class sumsq -----------
__global__ __launch_bounds__(256)
void k_rowsq(const float4* __restrict__ dotp, float4* __restrict__ dot,
             float* __restrict__ rowsq, int nchunk) {
    int t = blockIdx.x * 256 + threadIdx.x;       // 0..32767
    int lane = threadIdx.x & 63;
#pragma unroll
    for (int c = 0; c < NUM_CLASSES; c++) {
        float4 s = dotp[(size_t)c * NP4 + t];
        for (int g = 1; g < nchunk; g++) {
            float4 p = dotp[(size_t)(g * NUM_CLASSES + c) * NP4 + t];
            s.x += p.x; s.y += p.y; s.z += p.z; s.w += p.w;
        }
        dot[(size_t)c * NP4 + t] = s;
        float sq = s.x * s.x + s.y * s.y + s.z * s.z + s.w * s.w;
        sq = wave_reduce_sum(sq);
        if (lane == 0) atomicAdd(&rowsq[c], sq);
    }
}

// ---------------- Kernel E: log-softmax + picked + loss sum ---------------
__global__ __launch_bounds__(256)
void k_loss(const float* __restrict__ dot, const float* __restrict__ rowsq,
            const unsigned char* __restrict__ labels, float* __restrict__ lossacc) {
    int n = blockIdx.x * 256 + threadIdx.x;
    float l[NUM_CLASSES];
#pragma unroll
    for (int c = 0; c < NUM_CLASSES; c++) {
        float nrm = fmaxf(sqrtf(rowsq[c]), 1e-12f);
        l[c] = (dot[(size_t)c * NPIX + n] / nrm) * 10.0f;   // /TEMPERATURE
    }
    float m = l[0];
#pragma unroll
    for (int c = 1; c < NUM_CLASSES; c++) m = fmaxf(m, l[c]);
    float s = 0.f;
#pragma unroll
    for (int c = 0; c < NUM_CLASSES; c++) s += expf(l[c] - m);
    float lse = m + logf(s);

    int lab = labels[n];
    float lv = l[0];
#pragma unroll
    for (int c = 1; c < NUM_CLASSES; c++) lv = (lab == c) ? l[c] : lv;
    float picked = lv - lse;

    picked = wave_reduce_sum(picked);
    __shared__ float red[4];
    int wid = threadIdx.x >> 6, lane = threadIdx.x & 63;
    if (lane == 0) red[wid] = picked;
    __syncthreads();
    if (threadIdx.x == 0) {
        atomicAdd(lossacc, red[0] + red[1] + red[2] + red[3]);
    }
}

// ---------------- Kernel F: finalize --------------------------------------
__global__ void k_fin(const float* __restrict__ lossacc, float* __restrict__ out) {
    out[0] = -lossacc[0] * (1.0f / (float)NPIX);
}

extern "C" void kernel_launch(void* const* d_in, const int* in_sizes, int n_in,
                              void* d_out, int out_size, void* d_ws, size_t ws_size,
                              hipStream_t stream) {
    const float* feats    = (const float*)d_in[0];
    const int*   gt       = (const int*)d_in[1];
    const float* protos   = (const float*)d_in[2];
    float* out = (float*)d_out;

    char* ws = (char*)d_ws;
    int*   counts  = (int*)(ws + WS_COUNTS);
    float* rowsq   = (float*)(ws + WS_ROWSQ);
    float* lossacc = (float*)(ws + WS_LOSS);
    float* sums    = (float*)(ws + WS_SUMS);
    float* pnT     = (float*)(ws + WS_PNT);
    unsigned char* labels = (unsigned char*)(ws + WS_LABELS);
    float* dot     = (float*)(ws + WS_DOT);
    float4* dotp   = (float4*)(ws + WS_DOTP);

    // choose k-chunk count by available workspace (constant across calls)
    const size_t dot_part_bytes = (size_t)NUM_CLASSES * NPIX * 4;
    int nchunk = 1;
    if (ws_size >= WS_DOTP + 4 * dot_part_bytes) nchunk = 4;
    else if (ws_size >= WS_DOTP + 2 * dot_part_bytes) nchunk = 2;

    hipMemsetAsync(d_ws, 0, WS_ZERO_BYTES, stream);

    k_labels<<<NPIX / 256, 256, 0, stream>>>(gt, labels, counts);
    k_segsum<<<BATCH * CH, 256, 0, stream>>>((const float4*)feats,
                                             (const unsigned int*)labels, sums);
    k_protos<<<NUM_CLASSES, 256, 0, stream>>>(sums, counts, protos, pnT);

    if (nchunk == 4)
        k_dot<4><<<512, 256, 0, stream>>>((const float4*)feats, pnT, dotp);
    else if (nchunk == 2)
        k_dot<2><<<256, 256, 0, stream>>>((const float4*)feats, pnT, dotp);
    else
        k_dot<1><<<128, 256, 0, stream>>>((const float4*)feats, pnT, dotp);

    k_rowsq<<<NP4 / 256, 256, 0, stream>>>(dotp, (float4*)dot, rowsq, nchunk);
    k_loss<<<NPIX / 256, 256, 0, stream>>>(dot, rowsq, labels, lossacc);
    k_fin<<<1, 1, 0, stream>>>(lossacc, out);
}

// Round 3
// 685.362 us; speedup vs baseline: 1.2576x; 1.0142x over previous
//
#include <hip/hip_runtime.h>
#include <hip/hip_bf16.h>
#include <math.h>

// Problem constants
#define NUM_CLASSES 9
#define BATCH 8
#define CH 768
#define PLANE 16384             // (H/4)*(W/4)
#define NPIX (BATCH*PLANE)      // 131072
#define NP4 (NPIX/4)            // 32768 float4 pixel-groups

// Workspace layout (bytes)
#define WS_COUNTS   0                 // int[9]
#define WS_ROWSQ    64                // float[9]
#define WS_LOSS     128               // float[1]
#define WS_SUMS     256               // float[9*768]  -> ends 27904
#define WS_PNT      27904             // float[768*9] (k-major) -> ends 55552
#define WS_LABELS   55552             // uchar[131072] -> ends 186624
#define WS_DOT      186880            // float[9*131072] -> ends 4905472
#define WS_DOTP     4905472           // float[nchunk*9*131072] partial dots
#define WS_ZERO_BYTES 27904           // memset counts+rowsq+loss+sums

__device__ __forceinline__ float wave_reduce_sum(float v) {
#pragma unroll
    for (int off = 32; off > 0; off >>= 1) v += __shfl_down(v, off, 64);
    return v;
}

// ---------------- Kernel A: downsample labels + class counts -------------
__global__ __launch_bounds__(256)
void k_labels(const int* __restrict__ gt, unsigned char* __restrict__ labels,
              int* __restrict__ counts) {
    __shared__ int hist[NUM_CLASSES];
    int t = threadIdx.x;
    if (t < NUM_CLASSES) hist[t] = 0;
    __syncthreads();
    int n = blockIdx.x * 256 + t;                 // n < 131072
    int b = n >> 14;
    int rem = n & 16383;
    int i = rem >> 7, j = rem & 127;
    int lab = gt[b * 262144 + i * 2048 + j * 4];  // gt[b, 4i, 4j]
    labels[n] = (unsigned char)lab;
    atomicAdd(&hist[lab], 1);
    __syncthreads();
    if (t < NUM_CLASSES) atomicAdd(&counts[t], hist[t]);
}

// ---------------- Kernel B: per-class feature sums (LDS indexed bins) -----
// one block per (b,k) plane. Per-thread 2x9 bins in LDS, stride 19 (odd ->
// conflict-light). Two copies break the ds_read->ds_write dependency chain
// between the x/z and y/w sub-element updates.
#define SEG_STRIDE 19
__global__ __launch_bounds__(256)
void k_segsum(const float4* __restrict__ feats4, const unsigned int* __restrict__ lab4,
              float* __restrict__ sums) {
    __shared__ float lacc[256 * SEG_STRIDE];
    int t = threadIdx.x;
    float* my = &lacc[t * SEG_STRIDE];
#pragma unroll
    for (int c = 0; c < 18; c++) my[c] = 0.f;

    int bk = blockIdx.x;                // 0..6143
    int b  = bk / CH;
    int k  = bk - b * CH;
    const float4* plane = feats4 + ((size_t)bk << 12);
    const unsigned int* labs = lab4 + (b << 12);

#pragma unroll 4
    for (int i = t; i < 4096; i += 256) {
        float4 v = plane[i];
        unsigned int L = labs[i];
        // copy A: x,z   copy B (offset 9): y,w  -> 2 independent RMW chains
        my[L & 255]              += v.x;
        my[9 + ((L >> 8) & 255)] += v.y;
        my[(L >> 16) & 255]      += v.z;
        my[9 + (L >> 24)]        += v.w;
    }
    __syncthreads();

    int lane = t & 63;
#pragma unroll
    for (int c = 0; c < NUM_CLASSES; c++) {
        float v = lacc[t * SEG_STRIDE + c] + lacc[t * SEG_STRIDE + 9 + c];
        v = wave_reduce_sum(v);
        if (lane == 0) atomicAdd(&sums[c * CH + k], v);
    }
}

// ---------------- Kernel C: prototype update + row l2norm -----------------
__global__ __launch_bounds__(256)
void k_protos(const float* __restrict__ sums, const int* __restrict__ counts,
              const float* __restrict__ proto_in, float* __restrict__ pnT) {
    int c = blockIdx.x;
    int cnt = counts[c];
    float inv = 1.0f / fmaxf((float)cnt, 1.0f);
    bool pres = cnt > 0;

    float vals[3];
    float sq = 0.f;
#pragma unroll
    for (int r = 0; r < 3; r++) {
        int k = threadIdx.x + r * 256;
        float p = proto_in[c * CH + k];
        float m = sums[c * CH + k] * inv;
        float u = 0.99f * m + 0.01f * p;
        float v = pres ? u : p;
        vals[r] = v;
        sq += v * v;
    }
    sq = wave_reduce_sum(sq);
    __shared__ float red[4];
    int wid = threadIdx.x >> 6, lane = threadIdx.x & 63;
    if (lane == 0) red[wid] = sq;
    __syncthreads();
    float tot = red[0] + red[1] + red[2] + red[3];
    float nrm = fmaxf(sqrtf(tot), 1e-12f);
    float rinv = 1.0f / nrm;
#pragma unroll
    for (int r = 0; r < 3; r++) {
        int k = threadIdx.x + r * 256;
        pnT[k * NUM_CLASSES + c] = vals[r] * rinv;
    }
}

// ---------------- Kernel D: dot products (K-chunked, float4) --------------
// NCHUNK k-chunks x 128 blocks x 256 threads; 4 pixels per thread.
template<int NCHUNK>
__global__ __launch_bounds__(256, 2)
void k_dot(const float4* __restrict__ feats4, const float* __restrict__ pnT,
           float4* __restrict__ dotp) {
    constexpr int KC = CH / NCHUNK;
    int g = blockIdx.x >> 7;                       // k-chunk id
    int t = ((blockIdx.x & 127) << 8) + threadIdx.x;  // pixel-group 0..32767
    int b = t >> 12;
    int p4 = t & 4095;
    const float4* base = feats4 + (((size_t)(b * CH + g * KC)) << 12) + p4;
    const float* pw = pnT + g * KC * NUM_CLASSES;

    float4 acc[NUM_CLASSES];
#pragma unroll
    for (int c = 0; c < NUM_CLASSES; c++) acc[c] = make_float4(0.f, 0.f, 0.f, 0.f);

#pragma unroll 8
    for (int k = 0; k < KC; k++) {
        float4 v = base[(size_t)k << 12];
#pragma unroll
        for (int c = 0; c < NUM_CLASSES; c++) {
            float w = pw[k * NUM_CLASSES + c];
            acc[c].x = fmaf(w, v.x, acc[c].x);
            acc[c].y = fmaf(w, v.y, acc[c].y);
            acc[c].z = fmaf(w, v.z, acc[c].z);
            acc[c].w = fmaf(w, v.w, acc[c].w);
        }
    }
#pragma unroll
    for (int c = 0; c < NUM_CLASSES; c++)
        dotp[(size_t)(g * NUM_CLASSES + c) * NP4 + t] = acc[c];
}

// ---------------- Kernel D2: combine partials + per-class sumsq -----------
__global__ __launch_bounds__(256)
void k_rowsq(const float4* __restrict__ dotp, float4* __restrict__ dot,
             float* __restrict__ rowsq, int nchunk) {
    int t = blockIdx.x * 256 + threadIdx.x;       // 0..32767
    int lane = threadIdx.x & 63;
#pragma unroll
    for (int c = 0; c < NUM_CLASSES; c++) {
        float4 s = dotp[(size_t)c * NP4 + t];
        for (int g = 1; g < nchunk; g++) {
            float4 p = dotp[(size_t)(g * NUM_CLASSES + c) * NP4 + t];
            s.x += p.x; s.y += p.y; s.z += p.z; s.w += p.w;
        }
        dot[(size_t)c * NP4 + t] = s;
        float sq = s.x * s.x + s.y * s.y + s.z * s.z + s.w * s.w;
        sq = wave_reduce_sum(sq);
        if (lane == 0) atomicAdd(&rowsq[c], sq);
    }
}

// ---------------- Kernel E: log-softmax + picked + loss sum ---------------
__global__ __launch_bounds__(256)
void k_loss(const float* __restrict__ dot, const float* __restrict__ rowsq,
            const unsigned char* __restrict__ labels, float* __restrict__ lossacc) {
    int n = blockIdx.x * 256 + threadIdx.x;
    float l[NUM_CLASSES];
#pragma unroll
    for (int c = 0; c < NUM_CLASSES; c++) {
        float nrm = fmaxf(sqrtf(rowsq[c]), 1e-12f);
        l[c] = (dot[(size_t)c * NPIX + n] / nrm) * 10.0f;   // /TEMPERATURE
    }
    float m = l[0];
#pragma unroll
    for (int c = 1; c < NUM_CLASSES; c++) m = fmaxf(m, l[c]);
    float s = 0.f;
#pragma unroll
    for (int c = 0; c < NUM_CLASSES; c++) s += expf(l[c] - m);
    float lse = m + logf(s);

    int lab = labels[n];
    float lv = l[0];
#pragma unroll
    for (int c = 1; c < NUM_CLASSES; c++) lv = (lab == c) ? l[c] : lv;
    float picked = lv - lse;

    picked = wave_reduce_sum(picked);
    __shared__ float red[4];
    int wid = threadIdx.x >> 6, lane = threadIdx.x & 63;
    if (lane == 0) red[wid] = picked;
    __syncthreads();
    if (threadIdx.x == 0) {
        atomicAdd(lossacc, red[0] + red[1] + red[2] + red[3]);
    }
}

// ---------------- Kernel F: finalize --------------------------------------
__global__ void k_fin(const float* __restrict__ lossacc, float* __restrict__ out) {
    out[0] = -lossacc[0] * (1.0f / (float)NPIX);
}

extern "C" void kernel_launch(void* const* d_in, const int* in_sizes, int n_in,
                              void* d_out, int out_size, void* d_ws, size_t ws_size,
                              hipStream_t stream) {
    const float* feats    = (const float*)d_in[0];
    const int*   gt       = (const int*)d_in[1];
    const float* protos   = (const float*)d_in[2];
    float* out = (float*)d_out;

    char* ws = (char*)d_ws;
    int*   counts  = (int*)(ws + WS_COUNTS);
    float* rowsq   = (float*)(ws + WS_ROWSQ);
    float* lossacc = (float*)(ws + WS_LOSS);
    float* sums    = (float*)(ws + WS_SUMS);
    float* pnT     = (float*)(ws + WS_PNT);
    unsigned char* labels = (unsigned char*)(ws + WS_LABELS);
    float* dot     = (float*)(ws + WS_DOT);
    float4* dotp   = (float4*)(ws + WS_DOTP);

    // choose k-chunk count by available workspace (constant across calls)
    const size_t dot_part_bytes = (size_t)NUM_CLASSES * NPIX * 4;
    int nchunk = 1;
    if (ws_size >= WS_DOTP + 4 * dot_part_bytes) nchunk = 4;
    else if (ws_size >= WS_DOTP + 2 * dot_part_bytes) nchunk = 2;

    hipMemsetAsync(d_ws, 0, WS_ZERO_BYTES, stream);

    k_labels<<<NPIX / 256, 256, 0, stream>>>(gt, labels, counts);
    k_segsum<<<BATCH * CH, 256, 0, stream>>>((const float4*)feats,
                                             (const unsigned int*)labels, sums);
    k_protos<<<NUM_CLASSES, 256, 0, stream>>>(sums, counts, protos, pnT);

    if (nchunk == 4)
        k_dot<4><<<512, 256, 0, stream>>>((const float4*)feats, pnT, dotp);
    else if (nchunk == 2)
        k_dot<2><<<256, 256, 0, stream>>>((const float4*)feats, pnT, dotp);
    else
        k_dot<1><<<128, 256, 0, stream>>>((const float4*)feats, pnT, dotp);

    k_rowsq<<<NP4 / 256, 256, 0, stream>>>(dotp, (float4*)dot, rowsq, nchunk);
    k_loss<<<NPIX / 256, 256, 0, stream>>>(dot, rowsq, labels, lossacc);
    k_fin<<<1, 1, 0, stream>>>(lossacc, out);
}

// Round 4
// 680.893 us; speedup vs baseline: 1.2659x; 1.0066x over previous
//
#include <hip/hip_runtime.h>
#include <hip/hip_bf16.h>
#include <math.h>

// Problem constants
#define NUM_CLASSES 9
#define BATCH 8
#define CH 768
#define PLANE 16384             // (H/4)*(W/4)
#define NPIX (BATCH*PLANE)      // 131072
#define NP4 (NPIX/4)            // 32768 float4 pixel-groups

// Workspace layout (bytes)
#define WS_COUNTS   0                 // int[9]
#define WS_ROWSQ    64                // float[9]
#define WS_LOSS     128               // float[1]
#define WS_DONE     132               // int[1] done-counter for fused finalize
#define WS_SUMS     256               // float[9*768]  -> ends 27904
#define WS_PNT      27904             // float[768*9] (k-major) -> ends 55552
#define WS_LABELS   55552             // uchar[131072] -> ends 186624
#define WS_DOT      186880            // float[9*131072] -> ends 4905472
#define WS_DOTP     4905472           // float[nchunk*9*131072] partial dots
#define WS_ZERO_BYTES 27904           // memset counts+rowsq+loss+done+sums

__device__ __forceinline__ float wave_reduce_sum(float v) {
#pragma unroll
    for (int off = 32; off > 0; off >>= 1) v += __shfl_down(v, off, 64);
    return v;
}

// ---------------- Kernel A: downsample labels + class counts -------------
__global__ __launch_bounds__(256)
void k_labels(const int* __restrict__ gt, unsigned char* __restrict__ labels,
              int* __restrict__ counts) {
    __shared__ int hist[NUM_CLASSES];
    int t = threadIdx.x;
    if (t < NUM_CLASSES) hist[t] = 0;
    __syncthreads();
    int n = blockIdx.x * 256 + t;                 // n < 131072
    int b = n >> 14;
    int rem = n & 16383;
    int i = rem >> 7, j = rem & 127;
    int lab = gt[b * 262144 + i * 2048 + j * 4];  // gt[b, 4i, 4j]
    labels[n] = (unsigned char)lab;
    atomicAdd(&hist[lab], 1);
    __syncthreads();
    if (t < NUM_CLASSES) atomicAdd(&counts[t], hist[t]);
}

// ---------------- Kernel B: per-class feature sums (banked LDS bins) ------
// one block per (b,k) plane. Bins laid out [copy][class][thread] so every
// bin of thread t lives in bank t%32: within a wave only lanes (i, i+32)
// share a bank -> 2-way aliasing, which is free on gfx950 (m136).
// Two copies give two independent RMW dependency chains (x,z / y,w).
__global__ __launch_bounds__(256)
void k_segsum(const float4* __restrict__ feats4, const unsigned int* __restrict__ lab4,
              float* __restrict__ sums) {
    __shared__ float lacc[2 * NUM_CLASSES * 256];
    int t = threadIdx.x;
#pragma unroll
    for (int c = 0; c < 2 * NUM_CLASSES; c++) lacc[c * 256 + t] = 0.f;

    float* binA = &lacc[t];                       // copy 0: x, z
    float* binB = &lacc[NUM_CLASSES * 256 + t];   // copy 1: y, w

    int bk = blockIdx.x;                // 0..6143
    int b  = bk / CH;
    const float4* plane = feats4 + ((size_t)bk << 12);
    const unsigned int* labs = lab4 + (b << 12);

#pragma unroll 4
    for (int i = t; i < 4096; i += 256) {
        float4 v = plane[i];
        unsigned int L = labs[i];
        binA[(L & 255) << 8]         += v.x;
        binB[((L >> 8) & 255) << 8]  += v.y;
        binA[((L >> 16) & 255) << 8] += v.z;
        binB[(L >> 24) << 8]         += v.w;
    }
    __syncthreads();

    int k = bk - b * CH;
    int lane = t & 63;
#pragma unroll
    for (int c = 0; c < NUM_CLASSES; c++) {
        float v = lacc[c * 256 + t] + lacc[(NUM_CLASSES + c) * 256 + t];
        v = wave_reduce_sum(v);
        if (lane == 0) atomicAdd(&sums[c * CH + k], v);
    }
}

// ---------------- Kernel C: prototype update + row l2norm -----------------
__global__ __launch_bounds__(256)
void k_protos(const float* __restrict__ sums, const int* __restrict__ counts,
              const float* __restrict__ proto_in, float* __restrict__ pnT) {
    int c = blockIdx.x;
    int cnt = counts[c];
    float inv = 1.0f / fmaxf((float)cnt, 1.0f);
    bool pres = cnt > 0;

    float vals[3];
    float sq = 0.f;
#pragma unroll
    for (int r = 0; r < 3; r++) {
        int k = threadIdx.x + r * 256;
        float p = proto_in[c * CH + k];
        float m = sums[c * CH + k] * inv;
        float u = 0.99f * m + 0.01f * p;
        float v = pres ? u : p;
        vals[r] = v;
        sq += v * v;
    }
    sq = wave_reduce_sum(sq);
    __shared__ float red[4];
    int wid = threadIdx.x >> 6, lane = threadIdx.x & 63;
    if (lane == 0) red[wid] = sq;
    __syncthreads();
    float tot = red[0] + red[1] + red[2] + red[3];
    float nrm = fmaxf(sqrtf(tot), 1e-12f);
    float rinv = 1.0f / nrm;
#pragma unroll
    for (int r = 0; r < 3; r++) {
        int k = threadIdx.x + r * 256;
        pnT[k * NUM_CLASSES + c] = vals[r] * rinv;
    }
}

// ---------------- Kernel D: dot products (K-chunked, float4) --------------
// NCHUNK k-chunks x 128 blocks x 256 threads; 4 pixels per thread.
template<int NCHUNK>
__global__ __launch_bounds__(256, 2)
void k_dot(const float4* __restrict__ feats4, const float* __restrict__ pnT,
           float4* __restrict__ dotp) {
    constexpr int KC = CH / NCHUNK;
    int g = blockIdx.x >> 7;                       // k-chunk id
    int t = ((blockIdx.x & 127) << 8) + threadIdx.x;  // pixel-group 0..32767
    int b = t >> 12;
    int p4 = t & 4095;
    const float4* base = feats4 + (((size_t)(b * CH + g * KC)) << 12) + p4;
    const float* pw = pnT + g * KC * NUM_CLASSES;

    float4 acc[NUM_CLASSES];
#pragma unroll
    for (int c = 0; c < NUM_CLASSES; c++) acc[c] = make_float4(0.f, 0.f, 0.f, 0.f);

#pragma unroll 8
    for (int k = 0; k < KC; k++) {
        float4 v = base[(size_t)k << 12];
#pragma unroll
        for (int c = 0; c < NUM_CLASSES; c++) {
            float w = pw[k * NUM_CLASSES + c];
            acc[c].x = fmaf(w, v.x, acc[c].x);
            acc[c].y = fmaf(w, v.y, acc[c].y);
            acc[c].z = fmaf(w, v.z, acc[c].z);
            acc[c].w = fmaf(w, v.w, acc[c].w);
        }
    }
#pragma unroll
    for (int c = 0; c < NUM_CLASSES; c++)
        dotp[(size_t)(g * NUM_CLASSES + c) * NP4 + t] = acc[c];
}

// ---------------- Kernel D2: combine partials + per-class sumsq -----------
__global__ __launch_bounds__(256)
void k_rowsq(const float4* __restrict__ dotp, float4* __restrict__ dot,
             float* __restrict__ rowsq, int nchunk) {
    int t = blockIdx.x * 256 + threadIdx.x;       // 0..32767
    int lane = threadIdx.x & 63;
#pragma unroll
    for (int c = 0; c < NUM_CLASSES; c++) {
        float4 s = dotp[(size_t)c * NP4 + t];
        for (int g = 1; g < nchunk; g++) {
            float4 p = dotp[(size_t)(g * NUM_CLASSES + c) * NP4 + t];
            s.x += p.x; s.y += p.y; s.z += p.z; s.w += p.w;
        }
        dot[(size_t)c * NP4 + t] = s;
        float sq = s.x * s.x + s.y * s.y + s.z * s.z + s.w * s.w;
        sq = wave_reduce_sum(sq);
        if (lane == 0) atomicAdd(&rowsq[c], sq);
    }
}

// ---------------- Kernel E: log-softmax + picked + loss + finalize --------
__global__ __launch_bounds__(256)
void k_loss(const float* __restrict__ dot, const float* __restrict__ rowsq,
            const unsigned char* __restrict__ labels, float* __restrict__ lossacc,
            int* __restrict__ done, float* __restrict__ out, int nblocks) {
    int n = blockIdx.x * 256 + threadIdx.x;
    float l[NUM_CLASSES];
#pragma unroll
    for (int c = 0; c < NUM_CLASSES; c++) {
        float nrm = fmaxf(sqrtf(rowsq[c]), 1e-12f);
        l[c] = (dot[(size_t)c * NPIX + n] / nrm) * 10.0f;   // /TEMPERATURE
    }
    float m = l[0];
#pragma unroll
    for (int c = 1; c < NUM_CLASSES; c++) m = fmaxf(m, l[c]);
    float s = 0.f;
#pragma unroll
    for (int c = 0; c < NUM_CLASSES; c++) s += expf(l[c] - m);
    float lse = m + logf(s);

    int lab = labels[n];
    float lv = l[0];
#pragma unroll
    for (int c = 1; c < NUM_CLASSES; c++) lv = (lab == c) ? l[c] : lv;
    float picked = lv - lse;

    picked = wave_reduce_sum(picked);
    __shared__ float red[4];
    int wid = threadIdx.x >> 6, lane = threadIdx.x & 63;
    if (lane == 0) red[wid] = picked;
    __syncthreads();
    if (threadIdx.x == 0) {
        atomicAdd(lossacc, red[0] + red[1] + red[2] + red[3]);
        __threadfence();
        int prev = atomicAdd(done, 1);
        if (prev == nblocks - 1) {
            float total = atomicAdd(lossacc, 0.0f);   // read-back after all adds
            out[0] = -total * (1.0f / (float)NPIX);
        }
    }
}

extern "C" void kernel_launch(void* const* d_in, const int* in_sizes, int n_in,
                              void* d_out, int out_size, void* d_ws, size_t ws_size,
                              hipStream_t stream) {
    const float* feats    = (const float*)d_in[0];
    const int*   gt       = (const int*)d_in[1];
    const float* protos   = (const float*)d_in[2];
    float* out = (float*)d_out;

    char* ws = (char*)d_ws;
    int*   counts  = (int*)(ws + WS_COUNTS);
    float* rowsq   = (float*)(ws + WS_ROWSQ);
    float* lossacc = (float*)(ws + WS_LOSS);
    int*   done    = (int*)(ws + WS_DONE);
    float* sums    = (float*)(ws + WS_SUMS);
    float* pnT     = (float*)(ws + WS_PNT);
    unsigned char* labels = (unsigned char*)(ws + WS_LABELS);
    float* dot     = (float*)(ws + WS_DOT);
    float4* dotp   = (float4*)(ws + WS_DOTP);

    // choose k-chunk count by available workspace (constant across calls)
    const size_t dot_part_bytes = (size_t)NUM_CLASSES * NPIX * 4;
    int nchunk = 1;
    if (ws_size >= WS_DOTP + 4 * dot_part_bytes) nchunk = 4;
    else if (ws_size >= WS_DOTP + 2 * dot_part_bytes) nchunk = 2;

    hipMemsetAsync(d_ws, 0, WS_ZERO_BYTES, stream);

    k_labels<<<NPIX / 256, 256, 0, stream>>>(gt, labels, counts);
    k_segsum<<<BATCH * CH, 256, 0, stream>>>((const float4*)feats,
                                             (const unsigned int*)labels, sums);
    k_protos<<<NUM_CLASSES, 256, 0, stream>>>(sums, counts, protos, pnT);

    if (nchunk == 4)
        k_dot<4><<<512, 256, 0, stream>>>((const float4*)feats, pnT, dotp);
    else if (nchunk == 2)
        k_dot<2><<<256, 256, 0, stream>>>((const float4*)feats, pnT, dotp);
    else
        k_dot<1><<<128, 256, 0, stream>>>((const float4*)feats, pnT, dotp);

    k_rowsq<<<NP4 / 256, 256, 0, stream>>>(dotp, (float4*)dot, rowsq, nchunk);
    k_loss<<<NPIX / 256, 256, 0, stream>>>(dot, rowsq, labels, lossacc,
                                           done, out, NPIX / 256);
}